// Round 9
// baseline (7069.081 us; speedup 1.0000x reference)
//
#include <hip/hip_runtime.h>

#define B 256
#define T 2048
#define HDIM 128
#define CH 256
#define NCHUNK (T / CH)

typedef _Float16 f16;
typedef _Float16 h2 __attribute__((ext_vector_type(2)));
typedef _Float16 f16x8 __attribute__((ext_vector_type(8)));
typedef float f32x4 __attribute__((ext_vector_type(4)));

__device__ __forceinline__ float dot2(h2 a, h2 b, float c) {
#if __has_builtin(__builtin_amdgcn_fdot2)
    return __builtin_amdgcn_fdot2(a, b, c, false);
#else
    return c + (float)a[0] * (float)b[0] + (float)a[1] * (float)b[1];
#endif
}

__device__ __forceinline__ float rcp_(float x) {
#if __has_builtin(__builtin_amdgcn_rcpf)
    return __builtin_amdgcn_rcpf(x);
#else
    return 1.0f / x;
#endif
}
// approx activations via v_rcp (~1e-6 rel err; threshold is 1e-2)
__device__ __forceinline__ float sigm(float x) { return rcp_(1.0f + __expf(-x)); }
__device__ __forceinline__ float tanh_(float x) {
    float e = __expf(-2.0f * fabsf(x));
    float t = fmaf(2.0f, rcp_(1.0f + e), -1.0f);
    return copysignf(t, x);
}

__device__ __forceinline__ void bar() {
    // LDS-only barrier: order ds ops but do NOT drain vmcnt (keeps prefetch
    // loads and y-stores in flight across the barrier).
    asm volatile("s_waitcnt lgkmcnt(0)" ::: "memory");
    __builtin_amdgcn_s_barrier();
}

// ---------------- fc1: scent[B,T,3] -> x1[T,B,32] f16 (24 real + 8 zero pad) ---------
__global__ __launch_bounds__(256) void fc1_kernel(
    const float* __restrict__ scent,
    const float* __restrict__ W1, const float* __restrict__ b1,
    const float* __restrict__ W2, const float* __restrict__ b2,
    f16* __restrict__ x1) {
    int r = blockIdx.x * 256 + threadIdx.x;   // r = b*T + t
    int b = r >> 11, t = r & 2047;
    float s0 = scent[r * 3], s1 = scent[r * 3 + 1], s2 = scent[r * 3 + 2];
    float a[12];
#pragma unroll
    for (int i = 0; i < 12; i++) {
        float v = W1[i * 3] * s0 + W1[i * 3 + 1] * s1 + W1[i * 3 + 2] * s2 + b1[i];
        a[i] = fmaxf(v, 0.f);
    }
    union { f16 o[32]; uint4 u[4]; } U;
#pragma unroll
    for (int j = 0; j < 24; j++) {
        float v = b2[j];
#pragma unroll
        for (int i = 0; i < 12; i++) v = fmaf(W2[j * 12 + i], a[i], v);
        U.o[j] = (f16)fmaxf(v, 0.f);
    }
#pragma unroll
    for (int j = 24; j < 32; j++) U.o[j] = (f16)0.f;
    uint4* d4 = (uint4*)(x1 + ((size_t)t * B + b) * 32);
#pragma unroll
    for (int i = 0; i < 4; i++) d4[i] = U.u[i];
}

// ---------------- pack Wf1 f32 -> half2 ----------------
__global__ __launch_bounds__(256) void pack_kernel(const float* __restrict__ w,
                                                   unsigned int* __restrict__ o) {
    int i = blockIdx.x * 256 + threadIdx.x;
    if (i < 4096) {
        union { h2 h; unsigned int u; } U;
        U.h[0] = (f16)w[2 * i];
        U.h[1] = (f16)w[2 * i + 1];
        o[i] = U.u;
    }
}

// ---------------- gx pre-GEMM: gx[r,g] = x[r,:]@Wih^T + bih + bhh (one chunk) --------
template <int KIN, int KREAL, int SP>
__global__ __launch_bounds__(256) void gx_gemm(
    const f16* __restrict__ x,     // [T][B][KIN]
    const float* __restrict__ Wih, // [512][KREAL]
    const float* __restrict__ bih, const float* __restrict__ bhh,
    f16* __restrict__ gx,          // [CH*B][512]
    int t0) {
    constexpr int KF = KIN / 32;
    __shared__ __align__(16) f16 Alds[64 * SP];
    const int tid = threadIdx.x;
    const int mb = blockIdx.x, nb = blockIdx.y;
    const int l = tid & 63, wv = tid >> 6;
    const int lc = l & 15, lg = l >> 4;

    const f16* xrow = x + ((size_t)t0 * B + (size_t)mb * 64) * KIN;
    if (KIN == 128) {
#pragma unroll
        for (int it = 0; it < 4; it++) {
            int row = it * 16 + (tid >> 4), cc = tid & 15;
            uint4 v = *(const uint4*)(xrow + (size_t)row * KIN + cc * 8);
            *(uint4*)(&Alds[row * SP + cc * 8]) = v;
        }
    } else {
        int row = tid >> 2, cc = tid & 3;
        uint4 v = *(const uint4*)(xrow + (size_t)row * KIN + cc * 8);
        *(uint4*)(&Alds[row * SP + cc * 8]) = v;
    }

    const int gbase = nb * 128 + (wv & 1) * 64;
    const int rbase = (wv >> 1) * 32;
    f16x8 bf[4][KF];
    float bias4[4];
#pragma unroll
    for (int gt = 0; gt < 4; gt++) {
        int g = gbase + gt * 16 + lc;
        bias4[gt] = bih[g] + bhh[g];
#pragma unroll
        for (int kf = 0; kf < KF; kf++) {
            f16x8 v;
#pragma unroll
            for (int j = 0; j < 8; j++) {
                int k = kf * 32 + lg * 8 + j;
                v[j] = (k < KREAL) ? (f16)Wih[(size_t)g * KREAL + k] : (f16)0.f;
            }
            bf[gt][kf] = v;
        }
    }
    __syncthreads();

    f32x4 acc[2][4] = {};
#pragma unroll
    for (int kf = 0; kf < KF; kf++) {
#pragma unroll
        for (int rt = 0; rt < 2; rt++) {
            f16x8 af = *(const f16x8*)(&Alds[(rbase + rt * 16 + lc) * SP + kf * 32 + lg * 8]);
#pragma unroll
            for (int gt = 0; gt < 4; gt++)
                acc[rt][gt] = __builtin_amdgcn_mfma_f32_16x16x32_f16(af, bf[gt][kf], acc[rt][gt], 0, 0, 0);
        }
    }
#pragma unroll
    for (int rt = 0; rt < 2; rt++)
#pragma unroll
        for (int gt = 0; gt < 4; gt++)
#pragma unroll
            for (int q = 0; q < 4; q++) {
                int rr = mb * 64 + rbase + rt * 16 + lg * 4 + q;
                int gg = gbase + gt * 16 + lc;
                gx[(size_t)rr * 512 + gg] = (f16)(acc[rt][gt][q] + bias4[gt]);
            }
}

// ---------------- recurrence: one block (512 thr) per TWO batch rows, one chunk ------
// row = wave-bit (waves 0-3 -> row 2bb, waves 4-7 -> row 2bb+1): each SIMD hosts
// one wave of each row -> independent dot/act chains hide each other's latency.
// Within a row-group (256 thr): thread = (j = tl>>1 unit, q = tl&1 k-half), the
// r7-proven shape: 4 gate chains x 32 dot2, ONE shfl_xor(1), in-register cell
// update (redundant x2), single barrier, 4-deep gx ring.
__global__ __attribute__((amdgpu_flat_work_group_size(512, 512), amdgpu_waves_per_eu(2, 2)))
void lstm_rec(
    const f16* __restrict__ gx,    // [CH*B][512]
    const float* __restrict__ Whh, // [512][128]
    f16* __restrict__ y,           // [T][B][128]
    float* __restrict__ hS, float* __restrict__ cS,  // [B][128] state (= hT/cT out)
    int t0, int init) {
    __shared__ __align__(16) f16 hbuf[2][2][HDIM];   // [row][phase][unit]
    const int tid = threadIdx.x, bb = blockIdx.x;
    const int row = tid >> 8;        // 0: waves 0-3, 1: waves 4-7
    const int tl = tid & 255;
    const int j = tl >> 1, q = tl & 1;
    const int grow = 2 * bb + row;   // global batch row

    // ---- weights: gates {j, 128+j, 256+j, 384+j}, k in [64q, 64q+64) ----
    h2 wh[4][32];
#pragma unroll
    for (int gi = 0; gi < 4; gi++) {
        const float* wr = Whh + (size_t)(gi * 128 + j) * HDIM + 64 * q;
#pragma unroll
        for (int kk = 0; kk < 32; kk++) {
            h2 p; p[0] = (f16)wr[2 * kk]; p[1] = (f16)wr[2 * kk + 1];
            wh[gi][kk] = p;
        }
    }
    float c = 0.f;
    {
        float hv = 0.f;
        if (!init) { hv = hS[grow * HDIM + j]; c = cS[grow * HDIM + j]; }
        if (q == 0) hbuf[row][0][j] = (f16)hv;
    }
    // ---- gx prefetch ring (4 deep): q=0 lanes carry gates {0,1}=i,f; q=1 -> {2,3}=g,o
    const ushort* gp0 = (const ushort*)gx + (size_t)grow * 512 + (2 * q) * 128 + j;
    const ushort* gp1 = gp0 + 128;
    ushort ga[4], gb[4];
#pragma unroll
    for (int jj = 0; jj < 4; jj++) {
        ga[jj] = gp0[(size_t)jj * (B * 512)];
        gb[jj] = gp1[(size_t)jj * (B * 512)];
    }
    // y pointer, strength-reduced (advances by one step each iteration)
    f16* yp = y + ((size_t)t0 * B + grow) * HDIM + j;
    __syncthreads();

    float hh = 0.f;
    for (int w4 = 0; w4 < CH / 4; w4++) {
#pragma unroll
        for (int jj = 0; jj < 4; jj++) {
            const int t = w4 * 4 + jj;
            const int p = t & 1;
            union { ushort u; f16 h; } GA, GB;
            GA.u = ga[jj]; GB.u = gb[jj];
            float gxa = (float)GA.h, gxb = (float)GB.h;
            int tn = t + 4; if (tn > CH - 1) tn = CH - 1;
            ga[jj] = gp0[(size_t)tn * (B * 512)];
            gb[jj] = gp1[(size_t)tn * (B * 512)];

            // ---- slice read: 64 f16 of this row's h_{t-1} (8x b128, broadcast) ----
            union { uint4 u[8]; h2 h[32]; } S;
            {
                const uint4* kp = (const uint4*)(&hbuf[row][p][64 * q]);
#pragma unroll
                for (int i = 0; i < 8; i++) S.u[i] = kp[i];
            }
            // ---- partial dots for 4 gates; gx folded into acc init ----
            float acc[4];
            acc[0] = (q == 0) ? gxa : 0.f;
            acc[1] = (q == 0) ? gxb : 0.f;
            acc[2] = (q == 1) ? gxa : 0.f;
            acc[3] = (q == 1) ? gxb : 0.f;
#pragma unroll
            for (int kk = 0; kk < 32; kk++) {
#pragma unroll
                for (int gi = 0; gi < 4; gi++) acc[gi] = dot2(wh[gi][kk], S.h[kk], acc[gi]);
            }
            // ---- one butterfly level: both q-lanes get all 4 full gate sums ----
#pragma unroll
            for (int gi = 0; gi < 4; gi++) acc[gi] += __shfl_xor(acc[gi], 1);

            // ---- cell update (redundant on both q-lanes; bit-identical) ----
            float gi_ = sigm(acc[0]), gf_ = sigm(acc[1]);
            float gg_ = tanh_(acc[2]), go_ = sigm(acc[3]);
            c = gf_ * c + gi_ * gg_;
            hh = go_ * tanh_(c);
            if (q == 0) {
                hbuf[row][p ^ 1][j] = (f16)hh;
                *yp = (f16)hh;
            }
            yp += (size_t)B * HDIM;
            bar();
        }
    }
    if (q == 0) {
        hS[grow * HDIM + j] = hh;
        cS[grow * HDIM + j] = c;
    }
}

// ---------------- fc2: y[T,B,128] f16 -> out[B,T,32] f32 ----------------
__global__ __launch_bounds__(256) void fc2_kernel(
    const f16* __restrict__ yin,
    const unsigned int* __restrict__ w1,  // [64][64] half2-packed Wf1
    const float* __restrict__ bf1,
    const float* __restrict__ Wf2,        // [32][64] f32
    const float* __restrict__ bf2,
    float* __restrict__ out) {
    int r = blockIdx.x * 256 + threadIdx.x;   // r = t*B + b
    union { uint4 u4[16]; h2 h[64]; } Y;
    {
        const uint4* yr4 = (const uint4*)(yin + (size_t)r * 128);
#pragma unroll
        for (int i = 0; i < 16; i++) Y.u4[i] = yr4[i];
    }
    float acc2[32];
#pragma unroll
    for (int i = 0; i < 32; i++) acc2[i] = 0.f;

    for (int cO = 0; cO < 64; cO++) {   // rolled: z1[cO] consumed immediately
        float a0 = bf1[cO], a1 = 0.f, a2 = 0.f, a3 = 0.f;
#pragma unroll
        for (int kk = 0; kk < 64; kk += 4) {
            union { unsigned int u; h2 h; } W0, W1x, W2x, W3;
            W0.u = w1[cO * 64 + kk];      a0 = dot2(W0.h,  Y.h[kk],     a0);
            W1x.u = w1[cO * 64 + kk + 1]; a1 = dot2(W1x.h, Y.h[kk + 1], a1);
            W2x.u = w1[cO * 64 + kk + 2]; a2 = dot2(W2x.h, Y.h[kk + 2], a2);
            W3.u = w1[cO * 64 + kk + 3];  a3 = dot2(W3.h,  Y.h[kk + 3], a3);
        }
        float a = fmaxf((a0 + a1) + (a2 + a3), 0.f);
#pragma unroll
        for (int c2 = 0; c2 < 32; c2++) acc2[c2] = fmaf(a, Wf2[c2 * 64 + cO], acc2[c2]);
    }
    float* orow = out + ((size_t)(r & 255) * T + (r >> 8)) * 32;
#pragma unroll
    for (int c2 = 0; c2 < 32; c2++) orow[c2] = fmaxf(acc2[c2] + bf2[c2], 0.f);
}

// ---------------- launch ----------------
extern "C" void kernel_launch(void* const* d_in, const int* in_sizes, int n_in,
                              void* d_out, int out_size, void* d_ws, size_t ws_size,
                              hipStream_t stream) {
    const float* scent = (const float*)d_in[0];
    const float* W1 = (const float*)d_in[1];
    const float* b1 = (const float*)d_in[2];
    const float* W2 = (const float*)d_in[3];
    const float* b2 = (const float*)d_in[4];
    const float* Wih[3] = {(const float*)d_in[5], (const float*)d_in[9], (const float*)d_in[13]};
    const float* Whh[3] = {(const float*)d_in[6], (const float*)d_in[10], (const float*)d_in[14]};
    const float* bihp[3] = {(const float*)d_in[7], (const float*)d_in[11], (const float*)d_in[15]};
    const float* bhhp[3] = {(const float*)d_in[8], (const float*)d_in[12], (const float*)d_in[16]};
    const float* Wf1 = (const float*)d_in[17];
    const float* bf1 = (const float*)d_in[18];
    const float* Wf2 = (const float*)d_in[19];
    const float* bf2 = (const float*)d_in[20];

    const size_t o_x1 = 0;                       // 32 MB: x1 [T,B,32] f16
    const size_t o_y  = 33554432;                // 128 MB: yb [T,B,128] f16
    const size_t o_gx = o_y + 134217728;         // 64 MB: gx [CH,B,512] f16
    const size_t o_w1 = o_gx + 67108864;         // 16 KB: packed Wf1
    const size_t need = o_w1 + 16384;
    if (ws_size < need) return;

    char* ws = (char*)d_ws;
    f16* x1 = (f16*)(ws + o_x1);
    f16* yb = (f16*)(ws + o_y);
    f16* gxb = (f16*)(ws + o_gx);
    unsigned int* w1p = (unsigned int*)(ws + o_w1);

    float* out = (float*)d_out;
    float* hO = out + (size_t)B * T * 32;
    float* cO = hO + 3 * B * HDIM;

    pack_kernel<<<16, 256, 0, stream>>>(Wf1, w1p);
    fc1_kernel<<<(B * T) / 256, 256, 0, stream>>>(scent, W1, b1, W2, b2, x1);

    dim3 ggrid(CH * B / 64, 4);
    for (int l = 0; l < 3; l++) {
        float* hS = hO + (size_t)l * B * HDIM;
        float* cS = cO + (size_t)l * B * HDIM;
        for (int ch = 0; ch < NCHUNK; ch++) {
            int t0 = ch * CH;
            if (l == 0)
                gx_gemm<32, 24, 40><<<ggrid, 256, 0, stream>>>(x1, Wih[0], bihp[0], bhhp[0], gxb, t0);
            else
                gx_gemm<128, 128, 144><<<ggrid, 256, 0, stream>>>(yb, Wih[l], bihp[l], bhhp[l], gxb, t0);
            lstm_rec<<<B / 2, 512, 0, stream>>>(gxb, Whh[l], yb, hS, cS, t0, ch == 0 ? 1 : 0);
        }
    }
    fc2_kernel<<<(B * T) / 256, 256, 0, stream>>>(yb, w1p, bf1, Wf2, bf2, out);
}

// Round 10
// 5490.733 us; speedup vs baseline: 1.2875x; 1.2875x over previous
//
#include <hip/hip_runtime.h>

#define B 256
#define T 2048
#define HDIM 128

typedef _Float16 f16;
typedef _Float16 h2 __attribute__((ext_vector_type(2)));
typedef _Float16 f16x8 __attribute__((ext_vector_type(8)));
typedef float f32x4 __attribute__((ext_vector_type(4)));

__device__ __forceinline__ float dot2(h2 a, h2 b, float c) {
#if __has_builtin(__builtin_amdgcn_fdot2)
    return __builtin_amdgcn_fdot2(a, b, c, false);
#else
    return c + (float)a[0] * (float)b[0] + (float)a[1] * (float)b[1];
#endif
}

__device__ __forceinline__ float rcp_(float x) {
#if __has_builtin(__builtin_amdgcn_rcpf)
    return __builtin_amdgcn_rcpf(x);
#else
    return 1.0f / x;
#endif
}
// approx activations via v_rcp (~1e-6 rel err; threshold is 1e-2)
__device__ __forceinline__ float sigm(float x) { return rcp_(1.0f + __expf(-x)); }
// tanh(x) = 2*sigm(2x)-1; saturates correctly at +/-inf
__device__ __forceinline__ float tanh2(float x) {
    return fmaf(2.0f, rcp_(1.0f + __expf(-2.0f * x)), -1.0f);
}

__device__ __forceinline__ void bar() {
    // LDS-only barrier: order ds ops but do NOT drain vmcnt (x prefetch + y
    // stores stay in flight across the barrier).
    asm volatile("s_waitcnt lgkmcnt(0)" ::: "memory");
    __builtin_amdgcn_s_barrier();
}

// ---------------- fc1: scent[B,T,3] -> x1[T,B,32] f16 (24 real + 8 zero pad) ---------
__global__ __launch_bounds__(256) void fc1_kernel(
    const float* __restrict__ scent,
    const float* __restrict__ W1, const float* __restrict__ b1,
    const float* __restrict__ W2, const float* __restrict__ b2,
    f16* __restrict__ x1) {
    int r = blockIdx.x * 256 + threadIdx.x;   // r = b*T + t
    int b = r >> 11, t = r & 2047;
    float s0 = scent[r * 3], s1 = scent[r * 3 + 1], s2 = scent[r * 3 + 2];
    float a[12];
#pragma unroll
    for (int i = 0; i < 12; i++) {
        float v = W1[i * 3] * s0 + W1[i * 3 + 1] * s1 + W1[i * 3 + 2] * s2 + b1[i];
        a[i] = fmaxf(v, 0.f);
    }
    union { f16 o[32]; uint4 u[4]; } U;
#pragma unroll
    for (int j = 0; j < 24; j++) {
        float v = b2[j];
#pragma unroll
        for (int i = 0; i < 12; i++) v = fmaf(W2[j * 12 + i], a[i], v);
        U.o[j] = (f16)fmaxf(v, 0.f);
    }
#pragma unroll
    for (int j = 24; j < 32; j++) U.o[j] = (f16)0.f;
    uint4* d4 = (uint4*)(x1 + ((size_t)t * B + b) * 32);
#pragma unroll
    for (int i = 0; i < 4; i++) d4[i] = U.u[i];
}

// ---------------- pack Wf1 f32 -> half2 ----------------
__global__ __launch_bounds__(256) void pack_kernel(const float* __restrict__ w,
                                                   unsigned int* __restrict__ o) {
    int i = blockIdx.x * 256 + threadIdx.x;
    if (i < 4096) {
        union { h2 h; unsigned int u; } U;
        U.h[0] = (f16)w[2 * i];
        U.h[1] = (f16)w[2 * i + 1];
        o[i] = U.u;
    }
}

// ---------------- fused LSTM layer: one block (768 thr) per batch row, full T -------
// Waves 0-7 (rec): quad shape (j=tid>>2 unit, q=tid&3 32k-slice), wh[4][16]=64
//   dwords in VGPRs, 2-level DPP butterfly, in-register cell update, 1 bar/step.
//   gx values read from LDS window (no HBM ring).
// Waves 8-11 (gemm): compute gx windows 16 steps ahead on the MATRIX pipe:
//   per window 32 MFMA/wave; A = x frags (LDS, staged frag-major, dbuf);
//   B = Wih frags (RES resident in VGPRs + rest in LDS); C init = bias.
//   Slotted schedule: s==1 MFMA burst, s==3 gxw write, s==6 x load, s==10 x stage.
// gxw layout [buf][s][j*4+cls] (2-way-free rec reads); in-place x==y safe
// (read frontier t+32 > write frontier t).
template <int KF, int KREAL>
__global__ __attribute__((amdgpu_flat_work_group_size(768, 768), amdgpu_waves_per_eu(3, 3)))
void lstm_fused(
    const f16* x,                    // [T][B][KIN], KIN=KF*32 (may alias y)
    const float* __restrict__ Wih,   // [512][KREAL]
    const float* __restrict__ Whh,   // [512][128]
    const float* __restrict__ bih, const float* __restrict__ bhh,
    f16* y,                          // [T][B][128]
    float* __restrict__ hT, float* __restrict__ cT) {  // [B][128]
    constexpr int KIN = KF * 32;
    constexpr int RES = (KF == 1) ? 8 : 4;   // resident gate-tiles per gemm wave
    constexpr int NL = 32 - 4 * RES;         // gate-tiles stored in LDS (0 or 16)
    __shared__ __align__(16) f16 WiL[(NL > 0 ? NL : 1) * KF * 512];
    __shared__ __align__(16) f16 xb[2][KF * 512];    // A-frags, frag-major
    __shared__ __align__(16) f16 gxw[2][16 * 512];   // [s][j*4+cls]
    __shared__ __align__(16) f16 hbuf[2][HDIM];

    const int tid = threadIdx.x, bb = blockIdx.x;
    const int w = tid >> 6, l = tid & 63;
    const int lc = l & 15, lg = l >> 4;
    const int j = (tid & 511) >> 2, q = tid & 3;   // rec decomposition
    const int ww = w - 8;                          // gemm wave id

    // ---------------- persistent per-path state ----------------
    h2 wh[4][16];
    float msk[4];
    float c = 0.f, hl = 0.f;
    f16x8 resB[RES][KF];
    float bias8[8];
    f32x4 acc[8];
    uint4 xr0;

    if (w < 8) {
#pragma unroll
        for (int gi = 0; gi < 4; gi++) {
            const float* wr = Whh + (size_t)(gi * 128 + j) * HDIM + 32 * q;
#pragma unroll
            for (int kk = 0; kk < 16; kk++) {
                h2 p; p[0] = (f16)wr[2 * kk]; p[1] = (f16)wr[2 * kk + 1];
                wh[gi][kk] = p;
            }
            msk[gi] = (q == gi) ? 1.f : 0.f;
        }
        if (q == 0) hbuf[0][j] = (f16)0.f;
    } else {
#pragma unroll
        for (int r = 0; r < RES; r++) {
            int gt = ww * 8 + r;
#pragma unroll
            for (int kf = 0; kf < KF; kf++) {
                f16x8 v;
#pragma unroll
                for (int jj = 0; jj < 8; jj++) {
                    int k = kf * 32 + lg * 8 + jj;
                    v[jj] = (k < KREAL) ? (f16)Wih[(size_t)(gt * 16 + lc) * KREAL + k] : (f16)0.f;
                }
                resB[r][kf] = v;
            }
        }
#pragma unroll
        for (int gt8 = 0; gt8 < 8; gt8++) {
            int g = (ww * 8 + gt8) * 16 + lc;
            bias8[gt8] = bih[g] + bhh[g];
        }
    }

    // ---------------- one-time: stage non-resident Wih frags to LDS ----------------
    if (NL > 0) {
        for (int i = tid; i < NL * KF * 64; i += 768) {
            int gtL = i / (KF * 64);
            int rem = i - gtL * (KF * 64);
            int kf = rem >> 6, l2 = rem & 63;
            int wv2 = gtL / (8 - RES), idx = gtL % (8 - RES);
            int gt = wv2 * 8 + RES + idx;
            int g = gt * 16 + (l2 & 15);
            f16x8 v;
#pragma unroll
            for (int jj = 0; jj < 8; jj++) {
                int k = kf * 32 + (l2 >> 4) * 8 + jj;
                v[jj] = (k < KREAL) ? (f16)Wih[(size_t)g * KREAL + k] : (f16)0.f;
            }
            *(f16x8*)(&WiL[(size_t)i * 8]) = v;
        }
    }
    // ---------------- stage x windows 0,1 ----------------
    if (w >= 8 && ww < KF) {
        uint4 a0 = *(const uint4*)(x + (size_t)lc * (B * KIN) + bb * KIN + ww * 32 + lg * 8);
        uint4 a1 = *(const uint4*)(x + (size_t)(16 + lc) * (B * KIN) + bb * KIN + ww * 32 + lg * 8);
        *(uint4*)(&xb[0][(ww * 64 + l) * 8]) = a0;
        *(uint4*)(&xb[1][(ww * 64 + l) * 8]) = a1;
    }
    __syncthreads();

    // ---------------- prologue: gemm window 0 -> gxw[0] ----------------
    if (w >= 8) {
        f16x8 af[KF];
#pragma unroll
        for (int kf = 0; kf < KF; kf++) af[kf] = *(const f16x8*)(&xb[0][(kf * 64 + l) * 8]);
#pragma unroll
        for (int gt8 = 0; gt8 < 8; gt8++) {
            f32x4 a = {bias8[gt8], bias8[gt8], bias8[gt8], bias8[gt8]};
#pragma unroll
            for (int kf = 0; kf < KF; kf++) {
                f16x8 bf;
                if (gt8 < RES) bf = resB[gt8 & (RES - 1)][kf];
                else bf = *(const f16x8*)(&WiL[(size_t)(((ww * (8 - RES) + (gt8 - RES)) * KF + kf) * 64 + l) * 8]);
                a = __builtin_amdgcn_mfma_f32_16x16x32_f16(af[kf], bf, a, 0, 0, 0);
            }
#pragma unroll
            for (int qq = 0; qq < 4; qq++)
                gxw[0][(4 * lg + qq) * 512 + (gt8 * 16 + lc) * 4 + ww] = (f16)a[qq];
        }
    }
    __syncthreads();

    // ---------------- main loop ----------------
    f16* yp = y + (size_t)bb * HDIM + j;
    for (int t = 0; t < T; t++) {
        const int s = t & 15, W = t >> 4;
        const int pg = W & 1, ph = t & 1;
        if (w < 8) {
            float gxv = (float)gxw[pg][s * 512 + j * 4 + q];
            union { uint4 u[4]; h2 h[16]; } S;
            {
                const uint4* kp = (const uint4*)(&hbuf[ph][32 * q]);
#pragma unroll
                for (int i = 0; i < 4; i++) S.u[i] = kp[i];
            }
            float a0 = msk[0] * gxv, a1 = msk[1] * gxv, a2 = msk[2] * gxv, a3 = msk[3] * gxv;
#pragma unroll
            for (int kk = 0; kk < 16; kk++) {
                a0 = dot2(wh[0][kk], S.h[kk], a0);
                a1 = dot2(wh[1][kk], S.h[kk], a1);
                a2 = dot2(wh[2][kk], S.h[kk], a2);
                a3 = dot2(wh[3][kk], S.h[kk], a3);
            }
            a0 += __shfl_xor(a0, 1); a1 += __shfl_xor(a1, 1);
            a2 += __shfl_xor(a2, 1); a3 += __shfl_xor(a3, 1);
            a0 += __shfl_xor(a0, 2); a1 += __shfl_xor(a1, 2);
            a2 += __shfl_xor(a2, 2); a3 += __shfl_xor(a3, 2);
            float gi_ = sigm(a0), gf_ = sigm(a1), gg_ = tanh2(a2), go_ = sigm(a3);
            c = gf_ * c + gi_ * gg_;
            hl = go_ * tanh2(c);
            if (q == 0) {
                f16 h16 = (f16)hl;
                hbuf[ph ^ 1][j] = h16;
                *yp = h16;
            }
            yp += (size_t)B * HDIM;
        } else {
            if (s == 1) {
                // MFMA burst: gx for window W+1 from xb[(W+1)&1]
                f16x8 af[KF];
#pragma unroll
                for (int kf = 0; kf < KF; kf++)
                    af[kf] = *(const f16x8*)(&xb[(W + 1) & 1][(kf * 64 + l) * 8]);
#pragma unroll
                for (int gt8 = 0; gt8 < 8; gt8++) {
                    f32x4 a = {bias8[gt8], bias8[gt8], bias8[gt8], bias8[gt8]};
#pragma unroll
                    for (int kf = 0; kf < KF; kf++) {
                        f16x8 bf;
                        if (gt8 < RES) bf = resB[gt8 & (RES - 1)][kf];
                        else bf = *(const f16x8*)(&WiL[(size_t)(((ww * (8 - RES) + (gt8 - RES)) * KF + kf) * 64 + l) * 8]);
                        a = __builtin_amdgcn_mfma_f32_16x16x32_f16(af[kf], bf, a, 0, 0, 0);
                    }
                    acc[gt8] = a;
                }
            } else if (s == 3) {
                // write gx window W+1 into gxw[pg^1]
#pragma unroll
                for (int gt8 = 0; gt8 < 8; gt8++) {
#pragma unroll
                    for (int qq = 0; qq < 4; qq++)
                        gxw[pg ^ 1][(4 * lg + qq) * 512 + (gt8 * 16 + lc) * 4 + ww] = (f16)acc[gt8][qq];
                }
            } else if (s == 6) {
                if (ww < KF) {
                    int trow = (W + 2) * 16 + lc; if (trow > T - 1) trow = T - 1;
                    xr0 = *(const uint4*)(x + (size_t)trow * (B * KIN) + bb * KIN + ww * 32 + lg * 8);
                }
            } else if (s == 10) {
                if (ww < KF) *(uint4*)(&xb[W & 1][(ww * 64 + l) * 8]) = xr0;
            }
        }
        bar();
    }
    if (w < 8 && q == 0) {
        hT[(size_t)bb * HDIM + j] = hl;
        cT[(size_t)bb * HDIM + j] = c;
    }
}

// ---------------- fc2: y[T,B,128] f16 -> out[B,T,32] f32 ----------------
__global__ __launch_bounds__(256) void fc2_kernel(
    const f16* __restrict__ yin,
    const unsigned int* __restrict__ w1,  // [64][64] half2-packed Wf1
    const float* __restrict__ bf1,
    const float* __restrict__ Wf2,        // [32][64] f32
    const float* __restrict__ bf2,
    float* __restrict__ out) {
    int r = blockIdx.x * 256 + threadIdx.x;   // r = t*B + b
    union { uint4 u4[16]; h2 h[64]; } Y;
    {
        const uint4* yr4 = (const uint4*)(yin + (size_t)r * 128);
#pragma unroll
        for (int i = 0; i < 16; i++) Y.u4[i] = yr4[i];
    }
    float acc2[32];
#pragma unroll
    for (int i = 0; i < 32; i++) acc2[i] = 0.f;

    for (int cO = 0; cO < 64; cO++) {   // rolled: z1[cO] consumed immediately
        float a0 = bf1[cO], a1 = 0.f, a2 = 0.f, a3 = 0.f;
#pragma unroll
        for (int kk = 0; kk < 64; kk += 4) {
            union { unsigned int u; h2 h; } W0, W1x, W2x, W3;
            W0.u = w1[cO * 64 + kk];      a0 = dot2(W0.h,  Y.h[kk],     a0);
            W1x.u = w1[cO * 64 + kk + 1]; a1 = dot2(W1x.h, Y.h[kk + 1], a1);
            W2x.u = w1[cO * 64 + kk + 2]; a2 = dot2(W2x.h, Y.h[kk + 2], a2);
            W3.u = w1[cO * 64 + kk + 3];  a3 = dot2(W3.h,  Y.h[kk + 3], a3);
        }
        float a = fmaxf((a0 + a1) + (a2 + a3), 0.f);
#pragma unroll
        for (int c2 = 0; c2 < 32; c2++) acc2[c2] = fmaf(a, Wf2[c2 * 64 + cO], acc2[c2]);
    }
    float* orow = out + ((size_t)(r & 255) * T + (r >> 8)) * 32;
#pragma unroll
    for (int c2 = 0; c2 < 32; c2++) orow[c2] = fmaxf(acc2[c2] + bf2[c2], 0.f);
}

// ---------------- launch ----------------
extern "C" void kernel_launch(void* const* d_in, const int* in_sizes, int n_in,
                              void* d_out, int out_size, void* d_ws, size_t ws_size,
                              hipStream_t stream) {
    const float* scent = (const float*)d_in[0];
    const float* W1 = (const float*)d_in[1];
    const float* b1 = (const float*)d_in[2];
    const float* W2 = (const float*)d_in[3];
    const float* b2 = (const float*)d_in[4];
    const float* Wih[3] = {(const float*)d_in[5], (const float*)d_in[9], (const float*)d_in[13]};
    const float* Whh[3] = {(const float*)d_in[6], (const float*)d_in[10], (const float*)d_in[14]};
    const float* bihp[3] = {(const float*)d_in[7], (const float*)d_in[11], (const float*)d_in[15]};
    const float* bhhp[3] = {(const float*)d_in[8], (const float*)d_in[12], (const float*)d_in[16]};
    const float* Wf1 = (const float*)d_in[17];
    const float* bf1 = (const float*)d_in[18];
    const float* Wf2 = (const float*)d_in[19];
    const float* bf2 = (const float*)d_in[20];

    const size_t o_x1 = 0;                       // 32 MB: x1 [T,B,32] f16
    const size_t o_y  = 33554432;                // 128 MB: yb [T,B,128] f16
    const size_t o_w1 = o_y + 134217728;         // 16 KB: packed Wf1
    const size_t need = o_w1 + 16384;
    if (ws_size < need) return;

    char* ws = (char*)d_ws;
    f16* x1 = (f16*)(ws + o_x1);
    f16* yb = (f16*)(ws + o_y);
    unsigned int* w1p = (unsigned int*)(ws + o_w1);

    float* out = (float*)d_out;
    float* hO = out + (size_t)B * T * 32;
    float* cO = hO + 3 * B * HDIM;

    pack_kernel<<<16, 256, 0, stream>>>(Wf1, w1p);
    fc1_kernel<<<(B * T) / 256, 256, 0, stream>>>(scent, W1, b1, W2, b2, x1);

    lstm_fused<1, 24><<<B, 768, 0, stream>>>(x1, Wih[0], Whh[0], bihp[0], bhhp[0],
                                             yb, hO, cO);
    lstm_fused<4, 128><<<B, 768, 0, stream>>>(yb, Wih[1], Whh[1], bihp[1], bhhp[1],
                                              yb, hO + B * HDIM, cO + B * HDIM);
    lstm_fused<4, 128><<<B, 768, 0, stream>>>(yb, Wih[2], Whh[2], bihp[2], bhhp[2],
                                              yb, hO + 2 * B * HDIM, cO + 2 * B * HDIM);

    fc2_kernel<<<(B * T) / 256, 256, 0, stream>>>(yb, w1p, bf1, Wf2, bf2, out);
}

// Round 11
// 5177.313 us; speedup vs baseline: 1.3654x; 1.0605x over previous
//
#include <hip/hip_runtime.h>

#define B 256
#define T 2048
#define HDIM 128
#define CH 256
#define NCHUNK (T / CH)

typedef _Float16 f16;
typedef _Float16 h2 __attribute__((ext_vector_type(2)));
typedef _Float16 f16x8 __attribute__((ext_vector_type(8)));
typedef float f32x4 __attribute__((ext_vector_type(4)));

__device__ __forceinline__ float dot2(h2 a, h2 b, float c) {
#if __has_builtin(__builtin_amdgcn_fdot2)
    return __builtin_amdgcn_fdot2(a, b, c, false);
#else
    return c + (float)a[0] * (float)b[0] + (float)a[1] * (float)b[1];
#endif
}

__device__ __forceinline__ float rcp_(float x) {
#if __has_builtin(__builtin_amdgcn_rcpf)
    return __builtin_amdgcn_rcpf(x);
#else
    return 1.0f / x;
#endif
}
// approx activations via v_rcp (~1e-6 rel err; threshold is 1e-2)
__device__ __forceinline__ float sigm(float x) { return rcp_(1.0f + __expf(-x)); }
__device__ __forceinline__ float tanh_(float x) {
    float e = __expf(-2.0f * fabsf(x));
    float t = fmaf(2.0f, rcp_(1.0f + e), -1.0f);
    return copysignf(t, x);
}

// ---- quad-perm exchanges via DPP (pure VALU, ~4cy) -- replaces ds_bpermute
// __shfl_xor (LDS pipe, ~60cy serial latency in the reduce chain).
__device__ __forceinline__ float dpp_x1(float x) {   // lanes: 0<->1, 2<->3
#if __has_builtin(__builtin_amdgcn_update_dpp)
    union { float f; int i; } u, r;
    u.f = x;
    r.i = __builtin_amdgcn_update_dpp(0, u.i, 0xB1, 0xF, 0xF, true);  // quad_perm [1,0,3,2]
    return r.f;
#else
    return __shfl_xor(x, 1);
#endif
}
__device__ __forceinline__ float dpp_x2(float x) {   // lanes: 0<->2, 1<->3
#if __has_builtin(__builtin_amdgcn_update_dpp)
    union { float f; int i; } u, r;
    u.f = x;
    r.i = __builtin_amdgcn_update_dpp(0, u.i, 0x4E, 0xF, 0xF, true);  // quad_perm [2,3,0,1]
    return r.f;
#else
    return __shfl_xor(x, 2);
#endif
}

__device__ __forceinline__ void bar() {
    // LDS-only barrier: order ds ops but do NOT drain vmcnt (keeps prefetch
    // loads and y-stores in flight across the barrier).
    asm volatile("s_waitcnt lgkmcnt(0)" ::: "memory");
    __builtin_amdgcn_s_barrier();
}

// ---------------- fc1: scent[B,T,3] -> x1[T,B,32] f16 (24 real + 8 zero pad) ---------
__global__ __launch_bounds__(256) void fc1_kernel(
    const float* __restrict__ scent,
    const float* __restrict__ W1, const float* __restrict__ b1,
    const float* __restrict__ W2, const float* __restrict__ b2,
    f16* __restrict__ x1) {
    int r = blockIdx.x * 256 + threadIdx.x;   // r = b*T + t
    int b = r >> 11, t = r & 2047;
    float s0 = scent[r * 3], s1 = scent[r * 3 + 1], s2 = scent[r * 3 + 2];
    float a[12];
#pragma unroll
    for (int i = 0; i < 12; i++) {
        float v = W1[i * 3] * s0 + W1[i * 3 + 1] * s1 + W1[i * 3 + 2] * s2 + b1[i];
        a[i] = fmaxf(v, 0.f);
    }
    union { f16 o[32]; uint4 u[4]; } U;
#pragma unroll
    for (int j = 0; j < 24; j++) {
        float v = b2[j];
#pragma unroll
        for (int i = 0; i < 12; i++) v = fmaf(W2[j * 12 + i], a[i], v);
        U.o[j] = (f16)fmaxf(v, 0.f);
    }
#pragma unroll
    for (int j = 24; j < 32; j++) U.o[j] = (f16)0.f;
    uint4* d4 = (uint4*)(x1 + ((size_t)t * B + b) * 32);
#pragma unroll
    for (int i = 0; i < 4; i++) d4[i] = U.u[i];
}

// ---------------- pack Wf1 f32 -> half2 ----------------
__global__ __launch_bounds__(256) void pack_kernel(const float* __restrict__ w,
                                                   unsigned int* __restrict__ o) {
    int i = blockIdx.x * 256 + threadIdx.x;
    if (i < 4096) {
        union { h2 h; unsigned int u; } U;
        U.h[0] = (f16)w[2 * i];
        U.h[1] = (f16)w[2 * i + 1];
        o[i] = U.u;
    }
}

// ---------------- gx pre-GEMM: gx[r,g] = x[r,:]@Wih^T + bih + bhh (one chunk) --------
template <int KIN, int KREAL, int SP>
__global__ __launch_bounds__(256) void gx_gemm(
    const f16* __restrict__ x,     // [T][B][KIN]
    const float* __restrict__ Wih, // [512][KREAL]
    const float* __restrict__ bih, const float* __restrict__ bhh,
    f16* __restrict__ gx,          // [CH*B][512]
    int t0) {
    constexpr int KF = KIN / 32;
    __shared__ __align__(16) f16 Alds[64 * SP];
    const int tid = threadIdx.x;
    const int mb = blockIdx.x, nb = blockIdx.y;
    const int l = tid & 63, wv = tid >> 6;
    const int lc = l & 15, lg = l >> 4;

    const f16* xrow = x + ((size_t)t0 * B + (size_t)mb * 64) * KIN;
    if (KIN == 128) {
#pragma unroll
        for (int it = 0; it < 4; it++) {
            int row = it * 16 + (tid >> 4), cc = tid & 15;
            uint4 v = *(const uint4*)(xrow + (size_t)row * KIN + cc * 8);
            *(uint4*)(&Alds[row * SP + cc * 8]) = v;
        }
    } else {
        int row = tid >> 2, cc = tid & 3;
        uint4 v = *(const uint4*)(xrow + (size_t)row * KIN + cc * 8);
        *(uint4*)(&Alds[row * SP + cc * 8]) = v;
    }

    const int gbase = nb * 128 + (wv & 1) * 64;
    const int rbase = (wv >> 1) * 32;
    f16x8 bf[4][KF];
    float bias4[4];
#pragma unroll
    for (int gt = 0; gt < 4; gt++) {
        int g = gbase + gt * 16 + lc;
        bias4[gt] = bih[g] + bhh[g];
#pragma unroll
        for (int kf = 0; kf < KF; kf++) {
            f16x8 v;
#pragma unroll
            for (int j = 0; j < 8; j++) {
                int k = kf * 32 + lg * 8 + j;
                v[j] = (k < KREAL) ? (f16)Wih[(size_t)g * KREAL + k] : (f16)0.f;
            }
            bf[gt][kf] = v;
        }
    }
    __syncthreads();

    f32x4 acc[2][4] = {};
#pragma unroll
    for (int kf = 0; kf < KF; kf++) {
#pragma unroll
        for (int rt = 0; rt < 2; rt++) {
            f16x8 af = *(const f16x8*)(&Alds[(rbase + rt * 16 + lc) * SP + kf * 32 + lg * 8]);
#pragma unroll
            for (int gt = 0; gt < 4; gt++)
                acc[rt][gt] = __builtin_amdgcn_mfma_f32_16x16x32_f16(af, bf[gt][kf], acc[rt][gt], 0, 0, 0);
        }
    }
#pragma unroll
    for (int rt = 0; rt < 2; rt++)
#pragma unroll
        for (int gt = 0; gt < 4; gt++)
#pragma unroll
            for (int q = 0; q < 4; q++) {
                int rr = mb * 64 + rbase + rt * 16 + lg * 4 + q;
                int gg = gbase + gt * 16 + lc;
                gx[(size_t)rr * 512 + gg] = (f16)(acc[rt][gt][q] + bias4[gt]);
            }
}

// ---------------- recurrence: one block (512 thr) per batch row, one chunk ----------
// Quad decomposition (r6-proven clean: VGPR 88, conflicts 0): thread (j=tid>>2,
// q=tid&3) computes partial dots for ALL 4 gates of unit j over k-slice
// [32q,32q+32). 2-level DPP quad-perm reduce (VALU-only -- no ds_bpermute on the
// critical path) leaves all 4 gate sums on every lane; cell update in-register
// (redundant x4), no gbuf, ONE barrier/step, double-buffered hbuf.
__global__ __attribute__((amdgpu_flat_work_group_size(512, 512), amdgpu_waves_per_eu(2, 2)))
void lstm_rec(
    const f16* __restrict__ gx,    // [CH*B][512]
    const float* __restrict__ Whh, // [512][128]
    f16* __restrict__ y,           // [T][B][128]
    float* __restrict__ hS, float* __restrict__ cS,  // [B][128] state (= hT/cT out)
    int t0, int init) {
    __shared__ __align__(16) f16 hbuf[2][HDIM];
    const int tid = threadIdx.x, bb = blockIdx.x;
    const int j = tid >> 2, q = tid & 3;

    // ---- weights: gates {j, 128+j, 256+j, 384+j}, k in [32q, 32q+32) ----
    h2 wh[4][16];
#pragma unroll
    for (int gi = 0; gi < 4; gi++) {
        const float* wr = Whh + (size_t)(gi * 128 + j) * HDIM + 32 * q;
#pragma unroll
        for (int kk = 0; kk < 16; kk++) {
            h2 p; p[0] = (f16)wr[2 * kk]; p[1] = (f16)wr[2 * kk + 1];
            wh[gi][kk] = p;
        }
    }
    float c = 0.f;
    {
        float hv = 0.f;
        if (!init) { hv = hS[bb * HDIM + j]; c = cS[bb * HDIM + j]; }
        if (q == 0) hbuf[0][j] = (f16)hv;
    }
    // ---- gx prefetch ring (8 deep): thread reads gate q*128+j ----
    const ushort* gp = (const ushort*)gx + (size_t)bb * 512 + q * 128 + j;
    ushort gxr[8];
#pragma unroll
    for (int jj = 0; jj < 8; jj++) gxr[jj] = gp[(size_t)jj * (B * 512)];
    // y pointer, strength-reduced (advances one step per iteration)
    f16* yp = y + ((size_t)t0 * B + bb) * HDIM + j;
    __syncthreads();

    float hh = 0.f;
    for (int w8 = 0; w8 < CH / 8; w8++) {
#pragma unroll
        for (int jj = 0; jj < 8; jj++) {
            const int t = w8 * 8 + jj;
            const int p = t & 1;
            union { ushort u; f16 h; } GU; GU.u = gxr[jj];
            float gxv = (float)GU.h;
            int tn = t + 8; if (tn > CH - 1) tn = CH - 1;
            gxr[jj] = gp[(size_t)tn * (B * 512)];

            // ---- slice read: 32 f16 of h_{t-1} (4x b128; broadcast groups) ----
            union { uint4 u[4]; h2 h[16]; } S;
            {
                const uint4* kp = (const uint4*)(&hbuf[p][32 * q]);
                S.u[0] = kp[0]; S.u[1] = kp[1]; S.u[2] = kp[2]; S.u[3] = kp[3];
            }
            // ---- partial dots for 4 gates; gx folded into acc[q]'s gate ----
            float acc[4];
#pragma unroll
            for (int gi = 0; gi < 4; gi++) acc[gi] = (q == gi) ? gxv : 0.f;
#pragma unroll
            for (int kk = 0; kk < 16; kk++) {
#pragma unroll
                for (int gi = 0; gi < 4; gi++) acc[gi] = dot2(wh[gi][kk], S.h[kk], acc[gi]);
            }
            // ---- quad butterfly via DPP: every lane gets all 4 full gate sums ----
#pragma unroll
            for (int gi = 0; gi < 4; gi++) {
                acc[gi] += dpp_x1(acc[gi]);
                acc[gi] += dpp_x2(acc[gi]);
            }
            // ---- cell update (redundant on all 4 lanes; bit-identical) ----
            float gi_ = sigm(acc[0]), gf_ = sigm(acc[1]);
            float gg_ = tanh_(acc[2]), go_ = sigm(acc[3]);
            c = gf_ * c + gi_ * gg_;
            hh = go_ * tanh_(c);
            if (q == 0) {
                hbuf[p ^ 1][j] = (f16)hh;
                *yp = (f16)hh;
            }
            yp += (size_t)B * HDIM;
            bar();
        }
    }
    if (q == 0) {
        hS[bb * HDIM + j] = hh;
        cS[bb * HDIM + j] = c;
    }
}

// ---------------- fc2: y[T,B,128] f16 -> out[B,T,32] f32 ----------------
__global__ __launch_bounds__(256) void fc2_kernel(
    const f16* __restrict__ yin,
    const unsigned int* __restrict__ w1,  // [64][64] half2-packed Wf1
    const float* __restrict__ bf1,
    const float* __restrict__ Wf2,        // [32][64] f32
    const float* __restrict__ bf2,
    float* __restrict__ out) {
    int r = blockIdx.x * 256 + threadIdx.x;   // r = t*B + b
    union { uint4 u4[16]; h2 h[64]; } Y;
    {
        const uint4* yr4 = (const uint4*)(yin + (size_t)r * 128);
#pragma unroll
        for (int i = 0; i < 16; i++) Y.u4[i] = yr4[i];
    }
    float acc2[32];
#pragma unroll
    for (int i = 0; i < 32; i++) acc2[i] = 0.f;

    for (int cO = 0; cO < 64; cO++) {   // rolled: z1[cO] consumed immediately
        float a0 = bf1[cO], a1 = 0.f, a2 = 0.f, a3 = 0.f;
#pragma unroll
        for (int kk = 0; kk < 64; kk += 4) {
            union { unsigned int u; h2 h; } W0, W1x, W2x, W3;
            W0.u = w1[cO * 64 + kk];      a0 = dot2(W0.h,  Y.h[kk],     a0);
            W1x.u = w1[cO * 64 + kk + 1]; a1 = dot2(W1x.h, Y.h[kk + 1], a1);
            W2x.u = w1[cO * 64 + kk + 2]; a2 = dot2(W2x.h, Y.h[kk + 2], a2);
            W3.u = w1[cO * 64 + kk + 3];  a3 = dot2(W3.h,  Y.h[kk + 3], a3);
        }
        float a = fmaxf((a0 + a1) + (a2 + a3), 0.f);
#pragma unroll
        for (int c2 = 0; c2 < 32; c2++) acc2[c2] = fmaf(a, Wf2[c2 * 64 + cO], acc2[c2]);
    }
    float* orow = out + ((size_t)(r & 255) * T + (r >> 8)) * 32;
#pragma unroll
    for (int c2 = 0; c2 < 32; c2++) orow[c2] = fmaxf(acc2[c2] + bf2[c2], 0.f);
}

// ---------------- launch ----------------
extern "C" void kernel_launch(void* const* d_in, const int* in_sizes, int n_in,
                              void* d_out, int out_size, void* d_ws, size_t ws_size,
                              hipStream_t stream) {
    const float* scent = (const float*)d_in[0];
    const float* W1 = (const float*)d_in[1];
    const float* b1 = (const float*)d_in[2];
    const float* W2 = (const float*)d_in[3];
    const float* b2 = (const float*)d_in[4];
    const float* Wih[3] = {(const float*)d_in[5], (const float*)d_in[9], (const float*)d_in[13]};
    const float* Whh[3] = {(const float*)d_in[6], (const float*)d_in[10], (const float*)d_in[14]};
    const float* bihp[3] = {(const float*)d_in[7], (const float*)d_in[11], (const float*)d_in[15]};
    const float* bhhp[3] = {(const float*)d_in[8], (const float*)d_in[12], (const float*)d_in[16]};
    const float* Wf1 = (const float*)d_in[17];
    const float* bf1 = (const float*)d_in[18];
    const float* Wf2 = (const float*)d_in[19];
    const float* bf2 = (const float*)d_in[20];

    const size_t o_x1 = 0;                       // 32 MB: x1 [T,B,32] f16
    const size_t o_y  = 33554432;                // 128 MB: yb [T,B,128] f16
    const size_t o_gx = o_y + 134217728;         // 64 MB: gx [CH,B,512] f16
    const size_t o_w1 = o_gx + 67108864;         // 16 KB: packed Wf1
    const size_t need = o_w1 + 16384;
    if (ws_size < need) return;

    char* ws = (char*)d_ws;
    f16* x1 = (f16*)(ws + o_x1);
    f16* yb = (f16*)(ws + o_y);
    f16* gxb = (f16*)(ws + o_gx);
    unsigned int* w1p = (unsigned int*)(ws + o_w1);

    float* out = (float*)d_out;
    float* hO = out + (size_t)B * T * 32;
    float* cO = hO + 3 * B * HDIM;

    pack_kernel<<<16, 256, 0, stream>>>(Wf1, w1p);
    fc1_kernel<<<(B * T) / 256, 256, 0, stream>>>(scent, W1, b1, W2, b2, x1);

    dim3 ggrid(CH * B / 64, 4);
    for (int l = 0; l < 3; l++) {
        float* hS = hO + (size_t)l * B * HDIM;
        float* cS = cO + (size_t)l * B * HDIM;
        for (int ch = 0; ch < NCHUNK; ch++) {
            int t0 = ch * CH;
            if (l == 0)
                gx_gemm<32, 24, 40><<<ggrid, 256, 0, stream>>>(x1, Wih[0], bihp[0], bhhp[0], gxb, t0);
            else
                gx_gemm<128, 128, 144><<<ggrid, 256, 0, stream>>>(yb, Wih[l], bihp[l], bhhp[l], gxb, t0);
            lstm_rec<<<B, 512, 0, stream>>>(gxb, Whh[l], yb, hS, cS, t0, ch == 0 ? 1 : 0);
        }
    }
    fc2_kernel<<<(B * T) / 256, 256, 0, stream>>>(yb, w1p, bf1, Wf2, bf2, out);
}